// Round 1
// baseline (83.419 us; speedup 1.0000x reference)
//
#include <hip/hip_runtime.h>

// CSPN-style spatially-varying 7x7 filter.
// out[b,y,x] = sum_{i,j in [0,7)} gw[b, 7i+j, y+3, x+3] * src[b, y+3-i, x+3-j]
// src = hn except tap t==24 (i=j=3) which uses h0[b,y,x].
// Out-of-range hn reads are zero.

constexpr int B = 8, H = 512, W = 512, K = 7, HP = H + K - 1; // 518
constexpr long PLANE = (long)HP * HP;                          // 268324

__global__ __launch_bounds__(256) void cspn_kernel(
    const float* __restrict__ gw, const float* __restrict__ hn,
    const float* __restrict__ h0, float* __restrict__ out)
{
    int tid = blockIdx.x * 256 + threadIdx.x;
    int x = tid & (W - 1);          // 9 bits
    int y = (tid >> 9) & (H - 1);   // 9 bits
    int b = tid >> 18;

    // gw pointer for tap 0 at this pixel; tap t is at +t*PLANE.
    const float* gp = gw + (size_t)b * 49 * PLANE + (size_t)(y + 3) * HP + (x + 3);
    const float* hb = hn + (size_t)b * H * W;

    float acc = 0.f;
    #pragma unroll
    for (int i = 0; i < K; ++i) {
        int sy = y + 3 - i;                       // source row for this tap row
        bool oky = (unsigned)sy < (unsigned)H;    // block-uniform guard
        const float* hrow = hb + (size_t)(oky ? sy : 0) * W;
        #pragma unroll
        for (int j = 0; j < K; ++j) {
            int t = i * K + j;
            float g = gp[(size_t)t * PLANE];      // coalesced dword across lanes
            float v;
            if (t == 24) {
                // center tap: h0 at (y, x), always in-bounds
                v = h0[((size_t)b * H + y) * W + x];
            } else {
                int sx = x + 3 - j;
                bool ok = oky && ((unsigned)sx < (unsigned)W);
                v = ok ? hrow[sx] : 0.f;
            }
            acc += g * v;
        }
    }
    out[((size_t)b * H + y) * W + x] = acc;
}

extern "C" void kernel_launch(void* const* d_in, const int* in_sizes, int n_in,
                              void* d_out, int out_size, void* d_ws, size_t ws_size,
                              hipStream_t stream)
{
    const float* gw = (const float*)d_in[0];
    const float* hn = (const float*)d_in[1];
    const float* h0 = (const float*)d_in[2];
    float* out = (float*)d_out;

    int total = B * H * W;                 // 2,097,152 outputs
    int blocks = total / 256;              // 8192
    cspn_kernel<<<blocks, 256, 0, stream>>>(gw, hn, h0, out);
}